// Round 7
// baseline (38.423 us; speedup 1.0000x reference)
//
#include <hip/hip_runtime.h>

// N=4,000,000 pts, IN=5, MID=16, OUT=16, G=100,000 groups of 40.
// One wave processes GW groups; each group = 3 tiles of 16 points.
// mfma_f32_16x16x32_bf16 for both layers with a SPARSE k-embedding:
// element placement (q, dword, half) is IDENTICAL in A and B fragments, so the
// contraction is correct under any hardware k-layout (relabeling of k cancels).
//   layer1 dword0: q=0:(x0,x1) q=1:(x2,x3) q=2:(x4, 1.0), q=3: zero A (dummy B ok).
//   layer2 dwords0-1: mid chs 4q..4q+3  == layer-1 D regs of the SAME lane
//                     (D layout m89: col=lane&15=point, row=4*(lane>>4)+reg);
//   layer2 dword3 lo-half: b2 (A) x 1.0 (B), q==0 only  -> b2 folded pre-max.
// Round-7 changes vs round-6 (VALU-count attack; algorithm identical):
//   1) packbf = 4-op branchless round-half-up bit pack (was ~8-10 op RNE).
//   2) no divergent load guard: q==3 lanes dummy-load (their A-frag is zero).
//   3) loads rewritten as waveBase[xrow + compile-time-const] to get
//      saddr+voffset+imm codegen (zero per-load VALU address math).

using bf16x8 = __attribute__((ext_vector_type(8))) short;
using f32x4  = __attribute__((ext_vector_type(4))) float;
using u32x4  = __attribute__((ext_vector_type(4))) unsigned int;

constexpr int   N_PTS = 4000000;
constexpr int   GW    = 4;            // groups per wave; grid = 100000/(4*GW)
constexpr float SENT  = -1.0e30f;     // finite sentinel (cannot win a real max)

// round-half-up float->bf16 pair pack: 2 v_add + (v_and_or | v_perm) = ~3-4 VALU.
// Differs from RNE only on exact .5 ulp ties; inputs here are finite normals.
__device__ __forceinline__ unsigned packbf(float lo, float hi) {
    unsigned lu = __builtin_bit_cast(unsigned, lo) + 0x8000u;
    unsigned hu = __builtin_bit_cast(unsigned, hi) + 0x8000u;
    return (hu & 0xFFFF0000u) | (lu >> 16);
}

// all-reduce max across the 16 lanes of a DPP row via row_ror 8,4,2,1 (pure VALU)
__device__ __forceinline__ float dpp_max16(float v) {
    int x;
    x = __builtin_amdgcn_mov_dpp(__builtin_bit_cast(int, v), 0x128, 0xF, 0xF, false);
    v = fmaxf(v, __builtin_bit_cast(float, x));
    x = __builtin_amdgcn_mov_dpp(__builtin_bit_cast(int, v), 0x124, 0xF, 0xF, false);
    v = fmaxf(v, __builtin_bit_cast(float, x));
    x = __builtin_amdgcn_mov_dpp(__builtin_bit_cast(int, v), 0x122, 0xF, 0xF, false);
    v = fmaxf(v, __builtin_bit_cast(float, x));
    x = __builtin_amdgcn_mov_dpp(__builtin_bit_cast(int, v), 0x121, 0xF, 0xF, false);
    v = fmaxf(v, __builtin_bit_cast(float, x));
    return v;
}

__global__ __launch_bounds__(256)
void patch_mlp_max_mfma6(const float* __restrict__ data,
                         const float* __restrict__ gW1, const float* __restrict__ gb1,
                         const float* __restrict__ gW2, const float* __restrict__ gb2,
                         float* __restrict__ out)
{
    const int tid  = threadIdx.x;
    const int lane = tid & 63;
    const int wid  = tid >> 6;
    const int n    = lane & 15;   // point column / output channel (A row index)
    const int q    = lane >> 4;   // 16-lane row

    // ---- A1 fragment: row m=n (mid ch); dword0 pairs (W1[2q][n], W1[2q+1][n]|b1[n]) ----
    float wa = 0.f, wb = 0.f;
    if (q < 3) {
        wa = gW1[(2 * q) * 16 + n];
        wb = (q < 2) ? gW1[(2 * q + 1) * 16 + n] : gb1[n];
    }
    u32x4 a1u = {packbf(wa, wb), 0u, 0u, 0u};

    // ---- A2 fragment: row m=n (out ch); dwords0-1 = W2 chs 4q..4q+3; dword3 = bias ----
    const float w0 = gW2[(4 * q + 0) * 16 + n], w1 = gW2[(4 * q + 1) * 16 + n];
    const float w2 = gW2[(4 * q + 2) * 16 + n], w3 = gW2[(4 * q + 3) * 16 + n];
    const unsigned biasd = (q == 0) ? packbf(gb2[n], 0.f) : 0u;
    u32x4 a2u = {packbf(w0, w1), packbf(w2, w3), 0u, biasd};

    const bf16x8 a1 = __builtin_bit_cast(bf16x8, a1u);
    const bf16x8 a2 = __builtin_bit_cast(bf16x8, a2u);
    const unsigned b2const = (q == 0) ? packbf(1.0f, 0.f) : 0u;  // B-side bias slot
    const f32x4 zero4 = {0.f, 0.f, 0.f, 0.f};

    // q0:{x0,x1} q1:{x2,x3} q2:{x4,(1.0)} q3: dummy row-start (A-frag zero)
    const int  xoff    = (q < 3) ? 2 * q : 0;
    const int  xrow    = n * 5 + xoff;       // per-lane element offset, computed once
    const bool hi_load = (q < 2);

    const int    gbase = (blockIdx.x * 4 + wid) * GW;
    const float* base  = data + (size_t)gbase * 200;   // 40 pts * 5 floats per group

    #pragma unroll
    for (int gi = 0; gi < GW; ++gi) {
        const int g = gbase + gi;

        // ---- loads: base[xrow + const] -> saddr + voffset + imm, 0 VALU each ----
        float xa[3], xb[3];
        #pragma unroll
        for (int t = 0; t < 3; ++t) {
            int idx = xrow + gi * 200 + t * 80;
            if (t == 2 && (g * 40 + 32 + n) >= N_PTS) idx -= 80;  // final group straddle
            xa[t] = base[idx];
            xb[t] = hi_load ? base[idx + 1] : 1.0f;
        }

        f32x4 mrg = {SENT, SENT, SENT, SENT};

        #pragma unroll
        for (int t = 0; t < 3; ++t) {
            u32x4 bxu = {packbf(xa[t], xb[t]), 0u, 0u, 0u};

            f32x4 d1 = __builtin_amdgcn_mfma_f32_16x16x32_bf16(
                a1, __builtin_bit_cast(bf16x8, bxu), zero4, 0, 0, 0);

            // relu + pack: lane holds mid chs 4q..4q+3 of point n == its B2 slots
            const unsigned p0 = packbf(fmaxf(d1[0], 0.f), fmaxf(d1[1], 0.f));
            const unsigned p1 = packbf(fmaxf(d1[2], 0.f), fmaxf(d1[3], 0.f));
            u32x4 b2u = {p0, p1, 0u, b2const};

            f32x4 d2 = __builtin_amdgcn_mfma_f32_16x16x32_bf16(
                a2, __builtin_bit_cast(bf16x8, b2u), zero4, 0, 0, 0);

            const bool pvalid = (t < 2) | (n < 8);   // tile 2 has 8 valid points
            #pragma unroll
            for (int i = 0; i < 4; ++i) {
                const float v = pvalid ? d2[i] : SENT;
                mrg[i] = fmaxf(mrg[i], v);
            }
        }

        // ---- max across the 16 point columns (VALU only); b2 already folded ----
        float4 o;
        o.x = dpp_max16(mrg[0]);
        o.y = dpp_max16(mrg[1]);
        o.z = dpp_max16(mrg[2]);
        o.w = dpp_max16(mrg[3]);
        if (n == 0)
            *reinterpret_cast<float4*>(out + (size_t)g * 16 + q * 4) = o;
    }
}

extern "C" void kernel_launch(void* const* d_in, const int* in_sizes, int n_in,
                              void* d_out, int out_size, void* d_ws, size_t ws_size,
                              hipStream_t stream) {
    const float* data = (const float*)d_in[0];
    // d_in[1] = segment_ids: deterministic arange//40; unused.
    const float* W1 = (const float*)d_in[2];
    const float* b1 = (const float*)d_in[3];
    const float* W2 = (const float*)d_in[4];
    const float* b2 = (const float*)d_in[5];
    float* out = (float*)d_out;

    // 100000 groups / (4 waves/block * GW) = 6250 blocks
    dim3 grid(100000 / (4 * GW)), block(256);
    patch_mlp_max_mfma6<<<grid, block, 0, stream>>>(data, W1, b1, W2, b2, out);
}

// Round 8
// 33.285 us; speedup vs baseline: 1.1544x; 1.1544x over previous
//
#include <hip/hip_runtime.h>

// N=4,000,000 pts, IN=5, MID=16, OUT=16, G=100,000 groups of 40.
// One wave processes GW groups; each group = 3 tiles of 16 points.
// Layer 1 (verified r4-r7): A1 = W1 (row=mid ch), B1 = x (col=point), sparse
// k-embedding; D1 lane (n=point, q) holds mid chs 4q..4q+3 of point n.
// Layer 2 (NEW, transposed): A2 = activations (row m = point), B2 = W2
// (col = out ch, loop-invariant). A2's k-slots (q, dw0-1) = mid chs 4q..4q+3
// == D1's own registers -> p0,p1 feed A2 with zero cross-lane traffic.
// D2: col = lane&15 = OUT CHANNEL, row = 4q+reg = POINT. Segment max over
// points = 3 intra-lane fmax + shfl_xor(16) + shfl_xor(32). b2 folded into B2
// (k-slot (q=0,dw2,h0): A=1.0, B=b2[c]).
// Tile-2 trick: point columns n>=8 RE-LOAD in-group points 16+n (idx-80)
// instead of next-group points; duplicates are no-ops under max -> no masking,
// no cndmask, no N_PTS straddle check, and the wave never reads outside its
// own 4 groups.

using bf16x8 = __attribute__((ext_vector_type(8))) short;
using f32x4  = __attribute__((ext_vector_type(4))) float;
using u32x4  = __attribute__((ext_vector_type(4))) unsigned int;

constexpr int GW = 4;                 // groups per wave; grid = 100000/(4*GW)

// round-half-up float->bf16 pair pack (~3-4 VALU); ties differ from RNE only.
__device__ __forceinline__ unsigned packbf(float lo, float hi) {
    unsigned lu = __builtin_bit_cast(unsigned, lo) + 0x8000u;
    unsigned hu = __builtin_bit_cast(unsigned, hi) + 0x8000u;
    return (hu & 0xFFFF0000u) | (lu >> 16);
}

__global__ __launch_bounds__(256)
void patch_mlp_max_mfma7(const float* __restrict__ data,
                         const float* __restrict__ gW1, const float* __restrict__ gb1,
                         const float* __restrict__ gW2, const float* __restrict__ gb2,
                         float* __restrict__ out)
{
    const int tid  = threadIdx.x;
    const int lane = tid & 63;
    const int wid  = tid >> 6;
    const int n    = lane & 15;   // layer1: point col / layer2: out channel c
    const int q    = lane >> 4;   // 16-lane row group

    // ---- A1 = W1 row m=n (mid ch); dword0 = (W1[2q][n], W1[2q+1][n] | b1[n]) ----
    float wa = 0.f, wb = 0.f;
    if (q < 3) {
        wa = gW1[(2 * q) * 16 + n];
        wb = (q < 2) ? gW1[(2 * q + 1) * 16 + n] : gb1[n];
    }
    u32x4 a1u = {packbf(wa, wb), 0u, 0u, 0u};
    const bf16x8 a1 = __builtin_bit_cast(bf16x8, a1u);

    // ---- B2 = W2, col c=n (out ch); k-slots (q,dw,half): dw0=(W2[4q][c],W2[4q+1][c]),
    //      dw1=(W2[4q+2][c],W2[4q+3][c]), dw2 = q==0 ? (b2[c], 0) : 0 (bias slot) ----
    const float w0 = gW2[(4 * q + 0) * 16 + n], w1 = gW2[(4 * q + 1) * 16 + n];
    const float w2 = gW2[(4 * q + 2) * 16 + n], w3 = gW2[(4 * q + 3) * 16 + n];
    const unsigned biasd = (q == 0) ? packbf(gb2[n], 0.f) : 0u;
    u32x4 b2w = {packbf(w0, w1), packbf(w2, w3), biasd, 0u};
    const bf16x8 b2f = __builtin_bit_cast(bf16x8, b2w);
    const unsigned onepk = (q == 0) ? packbf(1.0f, 0.f) : 0u;  // A-side bias mult

    const f32x4 zero4 = {0.f, 0.f, 0.f, 0.f};

    // q0:{x0,x1} q1:{x2,x3} q2:{x4,(1.0)} q3: dummy in-bounds (A1 row is zero)
    const int  xoff  = (q < 3) ? 2 * q : 0;
    const int  xrowA = n * 5 + xoff;                    // tiles 0,1
    const int  xrowB = xrowA - ((n >= 8) ? 80 : 0);     // tile 2: dup in-group pts
    const bool hi_load = (q < 2);

    const int    gbase = (blockIdx.x * 4 + wid) * GW;
    const float* base  = data + (size_t)gbase * 200;    // 40 pts * 5 floats/group

    #pragma unroll
    for (int gi = 0; gi < GW; ++gi) {
        // ---- loads: base[lane_row + const]; all in this wave's 4 groups ----
        float xa[3], xb[3];
        #pragma unroll
        for (int t = 0; t < 3; ++t) {
            const int idx = ((t == 2) ? xrowB : xrowA) + gi * 200 + t * 80;
            xa[t] = base[idx];
            xb[t] = hi_load ? base[idx + 1] : 1.0f;
        }

        f32x4 mrg;
        #pragma unroll
        for (int t = 0; t < 3; ++t) {
            u32x4 bxu = {packbf(xa[t], xb[t]), 0u, 0u, 0u};

            f32x4 d1 = __builtin_amdgcn_mfma_f32_16x16x32_bf16(
                a1, __builtin_bit_cast(bf16x8, bxu), zero4, 0, 0, 0);

            // relu + pack: mid chs 4q..4q+3 of point n == A2 k-slots (q,dw0-1)
            const unsigned p0 = packbf(fmaxf(d1[0], 0.f), fmaxf(d1[1], 0.f));
            const unsigned p1 = packbf(fmaxf(d1[2], 0.f), fmaxf(d1[3], 0.f));
            u32x4 a2u = {p0, p1, onepk, 0u};

            // D2: col=out ch (n), row=point 4q+reg
            f32x4 d2 = __builtin_amdgcn_mfma_f32_16x16x32_bf16(
                __builtin_bit_cast(bf16x8, a2u), b2f, zero4, 0, 0, 0);

            if (t == 0) {
                mrg = d2;
            } else {
                #pragma unroll
                for (int i = 0; i < 4; ++i) mrg[i] = fmaxf(mrg[i], d2[i]);
            }
        }

        // ---- max over points: own 4 regs, then lanes ^16 and ^32 ----
        float v = fmaxf(fmaxf(mrg[0], mrg[1]), fmaxf(mrg[2], mrg[3]));
        v = fmaxf(v, __shfl_xor(v, 16, 64));
        v = fmaxf(v, __shfl_xor(v, 32, 64));

        // lanes q==0 hold all 16 channels -> one coalesced 64B row store
        if (q == 0)
            out[(size_t)(gbase + gi) * 16 + n] = v;
    }
}

extern "C" void kernel_launch(void* const* d_in, const int* in_sizes, int n_in,
                              void* d_out, int out_size, void* d_ws, size_t ws_size,
                              hipStream_t stream) {
    const float* data = (const float*)d_in[0];
    // d_in[1] = segment_ids: deterministic arange//40; unused.
    const float* W1 = (const float*)d_in[2];
    const float* b1 = (const float*)d_in[3];
    const float* W2 = (const float*)d_in[4];
    const float* b2 = (const float*)d_in[5];
    float* out = (float*)d_out;

    // 100000 groups / (4 waves/block * GW) = 6250 blocks
    dim3 grid(100000 / (4 * GW)), block(256);
    patch_mlp_max_mfma7<<<grid, block, 0, stream>>>(data, W1, b1, W2, b2, out);
}

// Round 9
// 32.754 us; speedup vs baseline: 1.1731x; 1.0162x over previous
//
#include <hip/hip_runtime.h>

// N=4,000,000 pts, IN=5, MID=16, OUT=16, G=100,000 groups of 40.
// One wave processes GW groups; each group = 3 tiles of 16 points.
// Layer 1 (verified r4-r8): A1 = W1 (row=mid ch), B1 = x (col=point), sparse
// k-embedding; D1 lane (n=point, q) holds mid chs 4q..4q+3 of point n.
// Layer 2 (verified r8, transposed): A2 = activations (row m = point),
// B2 = W2 (col = out ch, loop-invariant); D1's p0,p1 regs feed A2 directly.
// D2: col = out channel (n), row = point (4q+reg). Max over points = 3 fmax
// + shfl_xor(16) + shfl_xor(32). b2 folded into B2 bias k-slot.
// Tile-2 trick (r8): n>=8 re-loads in-group points n+16; dups no-op under max.
// Round-9 changes (latency attack; math byte-identical):
//   1) bulk prefetch: all GW*3*2 loads issued at wave start -> later groups'
//      loads overlap earlier groups' compute (was: load->use serial per group).
//   2) no exec-masked loads: hi-operand loaded unconditionally at precomputed
//      per-lane offset xrow+(q<2) (q>=2 re-reads own addr, L1 hit) + 1 cndmask.

using bf16x8 = __attribute__((ext_vector_type(8))) short;
using f32x4  = __attribute__((ext_vector_type(4))) float;
using u32x4  = __attribute__((ext_vector_type(4))) unsigned int;

constexpr int GW = 4;                 // groups per wave; grid = 100000/(4*GW)

// round-half-up float->bf16 pair pack (~3-4 VALU); ties differ from RNE only.
__device__ __forceinline__ unsigned packbf(float lo, float hi) {
    unsigned lu = __builtin_bit_cast(unsigned, lo) + 0x8000u;
    unsigned hu = __builtin_bit_cast(unsigned, hi) + 0x8000u;
    return (hu & 0xFFFF0000u) | (lu >> 16);
}

__global__ __launch_bounds__(256)
void patch_mlp_max_mfma8(const float* __restrict__ data,
                         const float* __restrict__ gW1, const float* __restrict__ gb1,
                         const float* __restrict__ gW2, const float* __restrict__ gb2,
                         float* __restrict__ out)
{
    const int tid  = threadIdx.x;
    const int lane = tid & 63;
    const int wid  = tid >> 6;
    const int n    = lane & 15;   // layer1: point col / layer2: out channel c
    const int q    = lane >> 4;   // 16-lane row group

    // ---- A1 = W1 row m=n (mid ch); dword0 = (W1[2q][n], W1[2q+1][n] | b1[n]) ----
    float wa = 0.f, wb = 0.f;
    if (q < 3) {
        wa = gW1[(2 * q) * 16 + n];
        wb = (q < 2) ? gW1[(2 * q + 1) * 16 + n] : gb1[n];
    }
    u32x4 a1u = {packbf(wa, wb), 0u, 0u, 0u};
    const bf16x8 a1 = __builtin_bit_cast(bf16x8, a1u);

    // ---- B2 = W2, col c=n (out ch); dw0=(W2[4q][c],W2[4q+1][c]),
    //      dw1=(W2[4q+2][c],W2[4q+3][c]), dw2 = q==0 ? (b2[c],0) : 0 ----
    const float w0 = gW2[(4 * q + 0) * 16 + n], w1 = gW2[(4 * q + 1) * 16 + n];
    const float w2 = gW2[(4 * q + 2) * 16 + n], w3 = gW2[(4 * q + 3) * 16 + n];
    const unsigned biasd = (q == 0) ? packbf(gb2[n], 0.f) : 0u;
    u32x4 b2w = {packbf(w0, w1), packbf(w2, w3), biasd, 0u};
    const bf16x8 b2f = __builtin_bit_cast(bf16x8, b2w);
    const unsigned onepk = (q == 0) ? packbf(1.0f, 0.f) : 0u;  // A-side bias mult

    const f32x4 zero4 = {0.f, 0.f, 0.f, 0.f};

    // q0:{x0,x1} q1:{x2,x3} q2:{x4,(1.0)} q3: dummy in-bounds (A1 row is zero)
    const int  xoff   = (q < 3) ? 2 * q : 0;
    const int  xrowA  = n * 5 + xoff;                    // tiles 0,1
    const int  xrowB  = xrowA - ((n >= 8) ? 80 : 0);     // tile 2: dup in-group pts
    const bool hi     = (q < 2);
    const int  xrowA2 = xrowA + (hi ? 1 : 0);            // hi-operand addr (safe for all q)
    const int  xrowB2 = xrowB + (hi ? 1 : 0);

    const int    gbase = (blockIdx.x * 4 + wid) * GW;
    const float* base  = data + (size_t)gbase * 200;     // 40 pts * 5 floats/group

    // ---- bulk prefetch: all GW groups x 3 tiles x {lo,hi}; saddr+voffset+imm ----
    float xa[GW][3], xh[GW][3];
    #pragma unroll
    for (int gi = 0; gi < GW; ++gi) {
        #pragma unroll
        for (int t = 0; t < 3; ++t) {
            const int c = gi * 200 + t * 80;
            xa[gi][t] = base[((t == 2) ? xrowB  : xrowA)  + c];
            xh[gi][t] = base[((t == 2) ? xrowB2 : xrowA2) + c];
        }
    }

    #pragma unroll
    for (int gi = 0; gi < GW; ++gi) {
        f32x4 mrg;
        #pragma unroll
        for (int t = 0; t < 3; ++t) {
            const float xbv = hi ? xh[gi][t] : 1.0f;   // one cndmask; q3 value is don't-care
            u32x4 bxu = {packbf(xa[gi][t], xbv), 0u, 0u, 0u};

            f32x4 d1 = __builtin_amdgcn_mfma_f32_16x16x32_bf16(
                a1, __builtin_bit_cast(bf16x8, bxu), zero4, 0, 0, 0);

            // relu + pack: mid chs 4q..4q+3 of point n == A2 k-slots (q,dw0-1)
            const unsigned p0 = packbf(fmaxf(d1[0], 0.f), fmaxf(d1[1], 0.f));
            const unsigned p1 = packbf(fmaxf(d1[2], 0.f), fmaxf(d1[3], 0.f));
            u32x4 a2u = {p0, p1, onepk, 0u};

            // D2: col=out ch (n), row=point 4q+reg
            f32x4 d2 = __builtin_amdgcn_mfma_f32_16x16x32_bf16(
                __builtin_bit_cast(bf16x8, a2u), b2f, zero4, 0, 0, 0);

            if (t == 0) {
                mrg = d2;
            } else {
                #pragma unroll
                for (int i = 0; i < 4; ++i) mrg[i] = fmaxf(mrg[i], d2[i]);
            }
        }

        // ---- max over points: own 4 regs, then lanes ^16 and ^32 ----
        float v = fmaxf(fmaxf(mrg[0], mrg[1]), fmaxf(mrg[2], mrg[3]));
        v = fmaxf(v, __shfl_xor(v, 16, 64));
        v = fmaxf(v, __shfl_xor(v, 32, 64));

        // lanes q==0 hold all 16 channels -> one coalesced 64B row store
        if (q == 0)
            out[(size_t)(gbase + gi) * 16 + n] = v;
    }
}

extern "C" void kernel_launch(void* const* d_in, const int* in_sizes, int n_in,
                              void* d_out, int out_size, void* d_ws, size_t ws_size,
                              hipStream_t stream) {
    const float* data = (const float*)d_in[0];
    // d_in[1] = segment_ids: deterministic arange//40; unused.
    const float* W1 = (const float*)d_in[2];
    const float* b1 = (const float*)d_in[3];
    const float* W2 = (const float*)d_in[4];
    const float* b2 = (const float*)d_in[5];
    float* out = (float*)d_out;

    // 100000 groups / (4 waves/block * GW) = 6250 blocks
    dim3 grid(100000 / (4 * GW)), block(256);
    patch_mlp_max_mfma8<<<grid, block, 0, stream>>>(data, W1, b1, W2, b2, out);
}

// Round 10
// 25.052 us; speedup vs baseline: 1.5337x; 1.3075x over previous
//
#include <hip/hip_runtime.h>

// N=4,000,000 pts, IN=5, MID=16, OUT=16, G=100,000 groups of 40.
// One wave = 8 groups = 320 points = EXACTLY 10 supertiles of 32 points.
// Both layers: mfma_f32_32x32x16_bf16 (D layout m74/m101-verified:
//   col = lane&31, row = (reg&3)+8*(reg>>2)+4*(lane>>5), reg in [0,16)).
// Layer 1: A1 = W1 (rows = mid chs 0-15; rows 16-31 zero), B1 = x (col = point
//   = lane&31). K-embedding split by lane half: half0 k-slots = (x0,x1),(x2,0);
//   half1 = (x3,x4),(b1-mult 1.0, 0). A-side zeros make B garbage don't-care ->
//   no exec masks. D1 regs 0-7 = relu-input mid chs {0-3,8-11}(h0)/{4-7,12-15}(h1)
//   of point lane&31; regs 8-15 = 0 (A rows 16-31) -> ignored.
// Layer 2: A2 = activations (row = point) = pack(relu(d1[0..7])) of the SAME
//   lane (zero-shuffle chain); B2 = W2 with the SAME sigma k-embedding:
//   half0 k-slots = chs {0,1,2,3,8,9,10,11}, half1 = {4,5,6,7,12,13,14,15}.
//   D2: col = out ch (lanes 16-31 duplicate cols via c&15), row = point.
// Segment max: group boundaries (mult of 40 = 0 mod 8) never split a reg's
//   (row,row+4) lane-half pair -> acc[(32s+rowbase)/40] is compile-time after
//   unroll; 16 plain fmax per supertile, zero masks. Epilogue: shfl_xor(32)
//   joins lane halves; b2 added after max (commutes); lanes<16 store rows.

using bf16x8 = __attribute__((ext_vector_type(8))) short;
using f32x16 = __attribute__((ext_vector_type(16))) float;
using u32x4  = __attribute__((ext_vector_type(4))) unsigned int;

constexpr float SENT = -1.0e30f;     // finite sentinel (cannot win a real max)

// round-half-up float->bf16 pair pack (~3-4 VALU); ties differ from RNE only.
__device__ __forceinline__ unsigned packbf(float lo, float hi) {
    unsigned lu = __builtin_bit_cast(unsigned, lo) + 0x8000u;
    unsigned hu = __builtin_bit_cast(unsigned, hi) + 0x8000u;
    return (hu & 0xFFFF0000u) | (lu >> 16);
}

__global__ __launch_bounds__(256)
void patch_mlp_max_mfma32(const float* __restrict__ data,
                          const float* __restrict__ gW1, const float* __restrict__ gb1,
                          const float* __restrict__ gW2, const float* __restrict__ gb2,
                          float* __restrict__ out)
{
    const int tid  = threadIdx.x;
    const int lane = tid & 63;
    const int wid  = tid >> 6;
    const int m31  = lane & 31;   // A/B row-col index; layer1 B col = point
    const int h    = lane >> 5;   // lane half = k-half

    // ---- A1 = W1: row m31 (mid ch, <16), k-halves per h ----
    float aw0 = 0.f, aw1 = 0.f, aw2 = 0.f;
    if (m31 < 16) {
        if (h == 0) { aw0 = gW1[0 * 16 + m31]; aw1 = gW1[1 * 16 + m31]; aw2 = gW1[2 * 16 + m31]; }
        else        { aw0 = gW1[3 * 16 + m31]; aw1 = gW1[4 * 16 + m31]; aw2 = gb1[m31]; }
    }
    u32x4 a1u = {packbf(aw0, aw1), packbf(aw2, 0.f), 0u, 0u};
    const bf16x8 a1 = __builtin_bit_cast(bf16x8, a1u);

    // ---- B2 = W2 with sigma k-embedding; col c = lane&15 (cols 16-31 dup) ----
    const int c  = lane & 15;
    const int k0 = h * 4;
    u32x4 b2u = {packbf(gW2[(k0 + 0)  * 16 + c], gW2[(k0 + 1)  * 16 + c]),
                 packbf(gW2[(k0 + 2)  * 16 + c], gW2[(k0 + 3)  * 16 + c]),
                 packbf(gW2[(k0 + 8)  * 16 + c], gW2[(k0 + 9)  * 16 + c]),
                 packbf(gW2[(k0 + 10) * 16 + c], gW2[(k0 + 11) * 16 + c])};
    const bf16x8 b2f = __builtin_bit_cast(bf16x8, b2u);
    const float  b2v = gb2[c];

    const f32x16 zero16 = {0.f, 0.f, 0.f, 0.f, 0.f, 0.f, 0.f, 0.f,
                           0.f, 0.f, 0.f, 0.f, 0.f, 0.f, 0.f, 0.f};

    // 8 groups per wave; 12500 waves total; zero tail anywhere.
    const int    gbase = (blockIdx.x * 4 + wid) * 8;
    const float* base  = data + (size_t)gbase * 200;   // 320 pts * 5 floats

    // x addressing: lane reads point m31; half0 floats {0,1,2}, half1 {3,4,(dup)}
    const int voA = m31 * 5 + (h ? 3 : 0);
    const int voC = voA + 2 - h;          // h1: dup of +1 (in-bounds, value unused)

    float acc[8];
    #pragma unroll
    for (int g = 0; g < 8; ++g) acc[g] = SENT;

    #pragma unroll
    for (int s = 0; s < 10; ++s) {
        const int sb = s * 160;           // 32 pts * 5 floats per supertile
        const float v0  = base[voA + sb];
        const float v1  = base[voA + sb + 1];
        const float v2l = base[voC + sb];
        const float v2  = h ? 1.0f : v2l;   // half1 k-slot 2 = bias multiplier

        u32x4 bxu = {packbf(v0, v1), packbf(v2, 0.f), 0u, 0u};
        f32x16 d1 = __builtin_amdgcn_mfma_f32_32x32x16_bf16(
            a1, __builtin_bit_cast(bf16x8, bxu), zero16, 0, 0, 0);

        // relu + pack regs 0-7 -> A2 (same-lane chain; regs 8-15 are zero rows)
        u32x4 a2u = {packbf(fmaxf(d1[0], 0.f), fmaxf(d1[1], 0.f)),
                     packbf(fmaxf(d1[2], 0.f), fmaxf(d1[3], 0.f)),
                     packbf(fmaxf(d1[4], 0.f), fmaxf(d1[5], 0.f)),
                     packbf(fmaxf(d1[6], 0.f), fmaxf(d1[7], 0.f))};
        f32x16 d2 = __builtin_amdgcn_mfma_f32_32x32x16_bf16(
            __builtin_bit_cast(bf16x8, a2u), b2f, zero16, 0, 0, 0);

        // merge rows (points) into per-group accs; index compile-time post-unroll
        #pragma unroll
        for (int r = 0; r < 16; ++r) {
            const int g = (32 * s + (r & 3) + 8 * (r >> 2)) / 40;
            acc[g] = fmaxf(acc[g], d2[r]);
        }
    }

    // ---- join lane halves (rows split by h), add b2 after max, store ----
    #pragma unroll
    for (int g = 0; g < 8; ++g)
        acc[g] = fmaxf(acc[g], __shfl_xor(acc[g], 32, 64));

    if (lane < 16) {
        #pragma unroll
        for (int g = 0; g < 8; ++g)
            out[(size_t)(gbase + g) * 16 + lane] = acc[g] + b2v;
    }
}

extern "C" void kernel_launch(void* const* d_in, const int* in_sizes, int n_in,
                              void* d_out, int out_size, void* d_ws, size_t ws_size,
                              hipStream_t stream) {
    const float* data = (const float*)d_in[0];
    // d_in[1] = segment_ids: deterministic arange//40; unused.
    const float* W1 = (const float*)d_in[2];
    const float* b1 = (const float*)d_in[3];
    const float* W2 = (const float*)d_in[4];
    const float* b2 = (const float*)d_in[5];
    float* out = (float*)d_out;

    // 100000 groups / (4 waves * 8 groups) = 3125 blocks exactly
    dim3 grid(3125), block(256);
    patch_mlp_max_mfma32<<<grid, block, 0, stream>>>(data, W1, b1, W2, b2, out);
}